// Round 1
// baseline (262.098 us; speedup 1.0000x reference)
//
#include <hip/hip_runtime.h>
#include <math.h>

#define BN 8
#define CN 64
#define HN 256
#define WN 256
#define HWN (HN * WN)          // 65536
#define NPIX (BN * HWN)        // 524288 pixels (b,h,w)
#define NTOT (BN * CN * HWN)   // 33554432 elements

struct DogK { float k[25]; };  // gk1 - gk2, 5x5 row-major

// Kernel 1: gray[b,h,w] = mean_c x[b,c,h,w]; float4 across w.
__global__ void gray_kernel(const float* __restrict__ x, float* __restrict__ gray) {
    int idx = blockIdx.x * blockDim.x + threadIdx.x;   // float4-pixel index
    if (idx >= NPIX / 4) return;
    int p4 = idx * 4;
    int b  = p4 / HWN;
    int hw = p4 - b * HWN;
    const float4* xp = (const float4*)(x + (size_t)b * CN * HWN + hw);
    float4 acc = make_float4(0.f, 0.f, 0.f, 0.f);
    #pragma unroll
    for (int c = 0; c < CN; ++c) {
        float4 v = xp[c * (HWN / 4)];
        acc.x += v.x; acc.y += v.y; acc.z += v.z; acc.w += v.w;
    }
    const float s = 1.0f / (float)CN;
    float4 g = make_float4(acc.x * s, acc.y * s, acc.z * s, acc.w * s);
    *(float4*)(gray + p4) = g;
}

// Kernel 2: dog = conv5x5(gray, k_dog), zero pad 2.
__global__ void dog_kernel(const float* __restrict__ gray, float* __restrict__ dog, DogK dk) {
    int idx = blockIdx.x * blockDim.x + threadIdx.x;
    if (idx >= NPIX) return;
    int b  = idx / HWN;
    int hw = idx - b * HWN;
    int h = hw / WN, w = hw - h * WN;
    const float* g = gray + b * HWN;
    float acc = 0.f;
    #pragma unroll
    for (int i = 0; i < 5; ++i) {
        int hh = h + i - 2;
        if (hh < 0 || hh >= HN) continue;
        #pragma unroll
        for (int j = 0; j < 5; ++j) {
            int ww = w + j - 2;
            if (ww < 0 || ww >= WN) continue;
            acc += dk.k[i * 5 + j] * g[hh * WN + ww];
        }
    }
    dog[idx] = acc;
}

// Kernel 3: sobel -> mag -> sigmoid gate; stores (1 + att).
__global__ void att_kernel(const float* __restrict__ dog, float* __restrict__ att1,
                           const float* __restrict__ gw, const float* __restrict__ gb) {
    int idx = blockIdx.x * blockDim.x + threadIdx.x;
    if (idx >= NPIX) return;
    int b  = idx / HWN;
    int hw = idx - b * HWN;
    int h = hw / WN, w = hw - h * WN;
    const float* d = dog + b * HWN;
    float v[3][3];
    #pragma unroll
    for (int i = 0; i < 3; ++i) {
        int hh = h + i - 1;
        #pragma unroll
        for (int j = 0; j < 3; ++j) {
            int ww = w + j - 1;
            v[i][j] = (hh >= 0 && hh < HN && ww >= 0 && ww < WN) ? d[hh * WN + ww] : 0.f;
        }
    }
    float gx = (v[0][2] - v[0][0]) + 2.f * (v[1][2] - v[1][0]) + (v[2][2] - v[2][0]);
    float gy = (v[2][0] - v[0][0]) + 2.f * (v[2][1] - v[0][1]) + (v[2][2] - v[0][2]);
    float mag = sqrtf(gx * gx + gy * gy + 1e-6f);
    float z = mag * gw[0] + gb[0];
    float a = 1.f / (1.f + expf(-z));
    att1[idx] = 1.0f + a;   // ALPHA = 1
}

// Kernel 4: out = x * att1[b,h,w], float4 vectorized.
__global__ void apply_kernel(const float* __restrict__ x, const float* __restrict__ att1,
                             float* __restrict__ out) {
    int idx = blockIdx.x * blockDim.x + threadIdx.x;   // float4 index
    if (idx >= NTOT / 4) return;
    int e  = idx * 4;
    int b  = e / (CN * HWN);
    int hw = e & (HWN - 1);            // HWN is pow2
    float4 xv = ((const float4*)x)[idx];
    float4 av = *(const float4*)(att1 + b * HWN + hw);
    float4 o = make_float4(xv.x * av.x, xv.y * av.y, xv.z * av.z, xv.w * av.w);
    ((float4*)out)[idx] = o;
}

extern "C" void kernel_launch(void* const* d_in, const int* in_sizes, int n_in,
                              void* d_out, int out_size, void* d_ws, size_t ws_size,
                              hipStream_t stream) {
    const float* x  = (const float*)d_in[0];
    const float* gw = (const float*)d_in[1];
    const float* gb = (const float*)d_in[2];
    float* out = (float*)d_out;

    float* gray = (float*)d_ws;          // NPIX floats
    float* dog  = gray + NPIX;           // NPIX floats
    float* att1 = gray;                  // reuse gray buffer (gray dead after dog_kernel)

    // Host-side DoG tap computation (pure CPU math; graph-capture safe).
    DogK dk;
    {
        double k1[25], k2[25], s1 = 0.0, s2 = 0.0;
        for (int i = 0; i < 5; ++i) {
            for (int j = 0; j < 5; ++j) {
                double di = i - 2.0, dj = j - 2.0;
                double r2 = di * di + dj * dj;
                k1[i * 5 + j] = exp(-r2 / (2.0 * 1.0 * 1.0));
                k2[i * 5 + j] = exp(-r2 / (2.0 * 2.0 * 2.0));
                s1 += k1[i * 5 + j];
                s2 += k2[i * 5 + j];
            }
        }
        for (int t = 0; t < 25; ++t)
            dk.k[t] = (float)(k1[t] / s1 - k2[t] / s2);
    }

    dim3 blk(256);
    gray_kernel<<<dim3((NPIX / 4 + 255) / 256), blk, 0, stream>>>(x, gray);
    dog_kernel <<<dim3((NPIX + 255) / 256),     blk, 0, stream>>>(gray, dog, dk);
    att_kernel <<<dim3((NPIX + 255) / 256),     blk, 0, stream>>>(dog, att1, gw, gb);
    apply_kernel<<<dim3((NTOT / 4 + 255) / 256), blk, 0, stream>>>(x, att1, out);
}